// Round 2
// baseline (2217.496 us; speedup 1.0000x reference)
//
#include <hip/hip_runtime.h>
#include <math.h>

#define N_MEMBERS 2
#define N_NODES   65536
#define N_EDGES   1048576
#define N_LAYERS  12
#define D         64
#define OFF_STRIDE (N_NODES + 1)
#define NODE_MASK (N_NODES - 1)

// ---------- preprocessing ----------

__global__ __launch_bounds__(256) void count_deg_k(const int* __restrict__ ei,
                                                   int* __restrict__ deg) {
    int e = blockIdx.x * 256 + threadIdx.x;
    int m = blockIdx.y;
    int dst = ei[(size_t)(m * 2 + 1) * N_EDGES + e] & NODE_MASK;
    atomicAdd(&deg[m * N_NODES + dst], 1);
}

__global__ __launch_bounds__(256) void dinv_k(const int* __restrict__ deg,
                                              float* __restrict__ dinv) {
    int i = blockIdx.x * 256 + threadIdx.x;   // over 2*N_NODES
    dinv[i] = 1.0f / sqrtf((float)deg[i] + 1.0f);
}

// ---- parallel 2-level exclusive scan of deg -> off ----
__global__ __launch_bounds__(256) void blocksum_k(const int* __restrict__ deg,
                                                  int* __restrict__ bs) {
    int m = blockIdx.y, blk = blockIdx.x, t = threadIdx.x;
    __shared__ int sh[256];
    sh[t] = deg[m * N_NODES + blk * 256 + t];
    __syncthreads();
    for (int ofs = 128; ofs > 0; ofs >>= 1) {
        if (t < ofs) sh[t] += sh[t + ofs];
        __syncthreads();
    }
    if (t == 0) bs[m * 256 + blk] = sh[0];
}

__global__ __launch_bounds__(256) void scan_bs_k(int* __restrict__ bs) {
    int m = blockIdx.x, t = threadIdx.x;
    __shared__ int sh[256];
    sh[t] = bs[m * 256 + t];
    __syncthreads();
    for (int ofs = 1; ofs < 256; ofs <<= 1) {
        int v = sh[t];
        int a = (t >= ofs) ? sh[t - ofs] : 0;
        __syncthreads();
        sh[t] = v + a;
        __syncthreads();
    }
    bs[m * 256 + t] = (t == 0) ? 0 : sh[t - 1];   // exclusive
}

__global__ __launch_bounds__(256) void scan_off_k(const int* __restrict__ deg,
                                                  const int* __restrict__ bs,
                                                  int* __restrict__ off) {
    int m = blockIdx.y, blk = blockIdx.x, t = threadIdx.x;
    int i = blk * 256 + t;
    int d = deg[m * N_NODES + i];
    __shared__ int sh[256];
    sh[t] = d;
    __syncthreads();
    for (int ofs = 1; ofs < 256; ofs <<= 1) {
        int v = sh[t];
        int a = (t >= ofs) ? sh[t - ofs] : 0;
        __syncthreads();
        sh[t] = v + a;
        __syncthreads();
    }
    off[m * OFF_STRIDE + i] = bs[m * 256 + blk] + sh[t] - d;  // exclusive
    if (i == N_NODES - 1) off[m * OFF_STRIDE + N_NODES] = N_EDGES;
}

// ---- CSR fill: one combined 8B (src, norm) store per edge ----
__global__ __launch_bounds__(256) void fill_k(const int* __restrict__ ei,
                                              const int* __restrict__ off,
                                              int* __restrict__ cursor,
                                              const float* __restrict__ dinv,
                                              int2* __restrict__ csr_es) {
    int e = blockIdx.x * 256 + threadIdx.x;
    int m = blockIdx.y;
    int src = ei[(size_t)(m * 2 + 0) * N_EDGES + e] & NODE_MASK;
    int dst = ei[(size_t)(m * 2 + 1) * N_EDGES + e] & NODE_MASK;
    int pos = off[m * OFF_STRIDE + dst] + atomicAdd(&cursor[m * N_NODES + dst], 1);
    float nrm = dinv[m * N_NODES + src] * dinv[m * N_NODES + dst];
    csr_es[(size_t)m * N_EDGES + pos] = make_int2(src, __float_as_int(nrm));
}

// ---------- per-layer: hw = h @ W[m][layer] (no bias) ----------
__global__ __launch_bounds__(256) void gemm_k(const float* __restrict__ h,
                                              const float* __restrict__ Wall,
                                              float* __restrict__ hw, int layer) {
    int m = blockIdx.y;
    const float* Wg = Wall + (size_t)(m * N_LAYERS + layer) * D * D;
    __shared__ float Wsh[D * D];
    {
        const float4* s4 = (const float4*)Wg;
        float4* d4 = (float4*)Wsh;
        for (int i = threadIdx.x; i < D * D / 4; i += 256) d4[i] = s4[i];
    }
    __syncthreads();
    int lane = threadIdx.x & 63;
    int wav  = threadIdx.x >> 6;
    float wreg[D];
    #pragma unroll
    for (int k = 0; k < D; k++) wreg[k] = Wsh[k * D + lane];

    const int NPW = 32;                       // nodes per wave
    int n0 = (blockIdx.x * 4 + wav) * NPW;
    const float* hm = h  + (size_t)m * N_NODES * D;
    float*       om = hw + (size_t)m * N_NODES * D;
    for (int n = n0; n < n0 + NPW; n++) {
        const float4* row = (const float4*)(hm + (size_t)n * D);
        float acc = 0.0f;
        #pragma unroll
        for (int k4 = 0; k4 < D / 4; k4++) {
            float4 a = row[k4];
            acc = fmaf(a.x, wreg[4 * k4 + 0], acc);
            acc = fmaf(a.y, wreg[4 * k4 + 1], acc);
            acc = fmaf(a.z, wreg[4 * k4 + 2], acc);
            acc = fmaf(a.w, wreg[4 * k4 + 3], acc);
        }
        om[(size_t)n * D + lane] = acc;
    }
}

// ---------- per-layer aggregate: 8-deep gather pipeline ----------
__global__ __launch_bounds__(256) void aggregate_k(const float* __restrict__ hw,
                                                   float* __restrict__ out,
                                                   const int* __restrict__ off,
                                                   const int2* __restrict__ csr_es,
                                                   const float* __restrict__ dinv,
                                                   const float* __restrict__ ball,
                                                   int layer, int relu) {
    int m = blockIdx.y;
    int n = blockIdx.x * 4 + (threadIdx.x >> 6);
    int lane = threadIdx.x & 63;
    const float* hm = hw + (size_t)m * N_NODES * D;
    const int*   ob = off + m * OFF_STRIDE;
    const int2*  eb = csr_es + (size_t)m * N_EDGES;

    float dv  = dinv[m * N_NODES + n];
    float acc = dv * dv * hm[(size_t)n * D + lane];

    int e0 = ob[n], e1 = ob[n + 1];
    int e = e0;
    for (; e + 8 <= e1; e += 8) {
        int2 p0 = eb[e];     int2 p1 = eb[e + 1];
        int2 p2 = eb[e + 2]; int2 p3 = eb[e + 3];
        int2 p4 = eb[e + 4]; int2 p5 = eb[e + 5];
        int2 p6 = eb[e + 6]; int2 p7 = eb[e + 7];
        float g0 = hm[(size_t)p0.x * D + lane];
        float g1 = hm[(size_t)p1.x * D + lane];
        float g2 = hm[(size_t)p2.x * D + lane];
        float g3 = hm[(size_t)p3.x * D + lane];
        float g4 = hm[(size_t)p4.x * D + lane];
        float g5 = hm[(size_t)p5.x * D + lane];
        float g6 = hm[(size_t)p6.x * D + lane];
        float g7 = hm[(size_t)p7.x * D + lane];
        acc = fmaf(__int_as_float(p0.y), g0, acc);
        acc = fmaf(__int_as_float(p1.y), g1, acc);
        acc = fmaf(__int_as_float(p2.y), g2, acc);
        acc = fmaf(__int_as_float(p3.y), g3, acc);
        acc = fmaf(__int_as_float(p4.y), g4, acc);
        acc = fmaf(__int_as_float(p5.y), g5, acc);
        acc = fmaf(__int_as_float(p6.y), g6, acc);
        acc = fmaf(__int_as_float(p7.y), g7, acc);
    }
    for (; e < e1; e++) {
        int2 p = eb[e];
        acc = fmaf(__int_as_float(p.y), hm[(size_t)p.x * D + lane], acc);
    }

    acc += ball[(size_t)(m * N_LAYERS + layer) * D + lane];
    if (relu) acc = fmaxf(acc, 0.0f);
    out[(size_t)m * N_NODES * D + (size_t)n * D + lane] = acc;
}

// ---------- host ----------

extern "C" void kernel_launch(void* const* d_in, const int* in_sizes, int n_in,
                              void* d_out, int out_size, void* d_ws, size_t ws_size,
                              hipStream_t stream) {
    (void)in_sizes; (void)n_in; (void)out_size; (void)ws_size;
    const float* x  = (const float*)d_in[0];
    const int*   ei = (const int*)d_in[1];
    const float* W  = (const float*)d_in[2];
    const float* b  = (const float*)d_in[3];
    float* out = (float*)d_out;

    char* ws = (char*)d_ws;
    size_t o = 0;
    auto take = [&](size_t bytes) -> void* {
        void* p = ws + o;
        o = (o + bytes + 255) & ~(size_t)255;
        return p;
    };
    int*   deg      = (int*)  take((size_t)N_MEMBERS * N_NODES * 4);
    int*   cursor   = (int*)  take((size_t)N_MEMBERS * N_NODES * 4);
    float* dinv     = (float*)take((size_t)N_MEMBERS * N_NODES * 4);
    int*   off      = (int*)  take((size_t)N_MEMBERS * OFF_STRIDE * 4);
    int*   bs       = (int*)  take((size_t)N_MEMBERS * 256 * 4);
    int2*  csr_es   = (int2*) take((size_t)N_MEMBERS * N_EDGES * 8);
    float* tbuf     = (float*)take((size_t)N_MEMBERS * N_NODES * D * 4);
    float* hbuf     = (float*)take((size_t)N_MEMBERS * N_NODES * D * 4);

    // zero deg + cursor (adjacent, both 256-padded)
    hipMemsetAsync(deg, 0, 2 * (size_t)N_MEMBERS * N_NODES * 4, stream);

    count_deg_k<<<dim3(N_EDGES / 256, N_MEMBERS), 256, 0, stream>>>(ei, deg);
    dinv_k<<<dim3((N_MEMBERS * N_NODES) / 256), 256, 0, stream>>>(deg, dinv);
    blocksum_k<<<dim3(N_NODES / 256, N_MEMBERS), 256, 0, stream>>>(deg, bs);
    scan_bs_k<<<dim3(N_MEMBERS), 256, 0, stream>>>(bs);
    scan_off_k<<<dim3(N_NODES / 256, N_MEMBERS), 256, 0, stream>>>(deg, bs, off);
    fill_k<<<dim3(N_EDGES / 256, N_MEMBERS), 256, 0, stream>>>(ei, off, cursor, dinv, csr_es);

    const float* hin = x;
    for (int j = 0; j < N_LAYERS; j++) {
        gemm_k<<<dim3(N_NODES / (4 * 32), N_MEMBERS), 256, 0, stream>>>(hin, W, tbuf, j);
        float* dst = (j == N_LAYERS - 1) ? out : hbuf;
        aggregate_k<<<dim3(N_NODES / 4, N_MEMBERS), 256, 0, stream>>>(
            tbuf, dst, off, csr_es, dinv, b, j, (j < N_LAYERS - 1) ? 1 : 0);
        hin = hbuf;
    }
}

// Round 3
// 1725.752 us; speedup vs baseline: 1.2849x; 1.2849x over previous
//
#include <hip/hip_runtime.h>
#include <hip/hip_fp16.h>
#include <math.h>

#define N_MEMBERS 2
#define N_NODES   65536
#define N_EDGES   1048576
#define N_LAYERS  12
#define D         64
#define OFF_STRIDE (N_NODES + 1)
#define NODE_MASK (N_NODES - 1)

// ---------- preprocessing ----------

__global__ __launch_bounds__(256) void count_deg_k(const int* __restrict__ ei,
                                                   int* __restrict__ deg) {
    int e = blockIdx.x * 256 + threadIdx.x;
    int m = blockIdx.y;
    int dst = ei[(size_t)(m * 2 + 1) * N_EDGES + e] & NODE_MASK;
    atomicAdd(&deg[m * N_NODES + dst], 1);
}

__global__ __launch_bounds__(256) void dinv_k(const int* __restrict__ deg,
                                              float* __restrict__ dinv) {
    int i = blockIdx.x * 256 + threadIdx.x;   // over 2*N_NODES
    dinv[i] = 1.0f / sqrtf((float)deg[i] + 1.0f);
}

// ---- parallel 2-level exclusive scan of deg -> off ----
__global__ __launch_bounds__(256) void blocksum_k(const int* __restrict__ deg,
                                                  int* __restrict__ bs) {
    int m = blockIdx.y, blk = blockIdx.x, t = threadIdx.x;
    __shared__ int sh[256];
    sh[t] = deg[m * N_NODES + blk * 256 + t];
    __syncthreads();
    for (int ofs = 128; ofs > 0; ofs >>= 1) {
        if (t < ofs) sh[t] += sh[t + ofs];
        __syncthreads();
    }
    if (t == 0) bs[m * 256 + blk] = sh[0];
}

__global__ __launch_bounds__(256) void scan_bs_k(int* __restrict__ bs) {
    int m = blockIdx.x, t = threadIdx.x;
    __shared__ int sh[256];
    sh[t] = bs[m * 256 + t];
    __syncthreads();
    for (int ofs = 1; ofs < 256; ofs <<= 1) {
        int v = sh[t];
        int a = (t >= ofs) ? sh[t - ofs] : 0;
        __syncthreads();
        sh[t] = v + a;
        __syncthreads();
    }
    bs[m * 256 + t] = (t == 0) ? 0 : sh[t - 1];   // exclusive
}

__global__ __launch_bounds__(256) void scan_off_k(const int* __restrict__ deg,
                                                  const int* __restrict__ bs,
                                                  int* __restrict__ off) {
    int m = blockIdx.y, blk = blockIdx.x, t = threadIdx.x;
    int i = blk * 256 + t;
    int d = deg[m * N_NODES + i];
    __shared__ int sh[256];
    sh[t] = d;
    __syncthreads();
    for (int ofs = 1; ofs < 256; ofs <<= 1) {
        int v = sh[t];
        int a = (t >= ofs) ? sh[t - ofs] : 0;
        __syncthreads();
        sh[t] = v + a;
        __syncthreads();
    }
    off[m * OFF_STRIDE + i] = bs[m * 256 + blk] + sh[t] - d;  // exclusive
    if (i == N_NODES - 1) off[m * OFF_STRIDE + N_NODES] = N_EDGES;
}

// ---- CSR fill: one combined 8B (src, norm) store per edge ----
__global__ __launch_bounds__(256) void fill_k(const int* __restrict__ ei,
                                              const int* __restrict__ off,
                                              int* __restrict__ cursor,
                                              const float* __restrict__ dinv,
                                              int2* __restrict__ csr_es) {
    int e = blockIdx.x * 256 + threadIdx.x;
    int m = blockIdx.y;
    int src = ei[(size_t)(m * 2 + 0) * N_EDGES + e] & NODE_MASK;
    int dst = ei[(size_t)(m * 2 + 1) * N_EDGES + e] & NODE_MASK;
    int pos = off[m * OFF_STRIDE + dst] + atomicAdd(&cursor[m * N_NODES + dst], 1);
    float nrm = dinv[m * N_NODES + src] * dinv[m * N_NODES + dst];
    csr_es[(size_t)m * N_EDGES + pos] = make_int2(src, __float_as_int(nrm));
}

// ---------- per-layer: hw = h @ W[m][layer] (fp16 out, LDS-staged h) ----------
__global__ __launch_bounds__(256) void gemm_k(const float* __restrict__ h,
                                              const float* __restrict__ Wall,
                                              __half* __restrict__ hw, int layer) {
    int m = blockIdx.y;
    const float* Wg = Wall + (size_t)(m * N_LAYERS + layer) * D * D;
    __shared__ float Wsh[D * D];        // 16 KB
    __shared__ float Hsh[128 * D];      // 32 KB
    for (int i = threadIdx.x; i < D * D / 4; i += 256)
        ((float4*)Wsh)[i] = ((const float4*)Wg)[i];
    int n0 = blockIdx.x * 128;
    const float* hm = h + (size_t)m * N_NODES * D + (size_t)n0 * D;
    for (int i = threadIdx.x; i < 128 * D / 4; i += 256)
        ((float4*)Hsh)[i] = ((const float4*)hm)[i];
    __syncthreads();

    int lane = threadIdx.x & 63;
    int wav  = threadIdx.x >> 6;
    float wreg[D];
    #pragma unroll
    for (int k = 0; k < D; k++) wreg[k] = Wsh[k * D + lane];

    __half* om = hw + (size_t)m * N_NODES * D + (size_t)n0 * D;
    for (int r = wav * 32; r < wav * 32 + 32; r++) {
        const float4* row = (const float4*)(Hsh + r * D);
        float acc = 0.0f;
        #pragma unroll
        for (int k4 = 0; k4 < D / 4; k4++) {
            float4 a = row[k4];
            acc = fmaf(a.x, wreg[4 * k4 + 0], acc);
            acc = fmaf(a.y, wreg[4 * k4 + 1], acc);
            acc = fmaf(a.z, wreg[4 * k4 + 2], acc);
            acc = fmaf(a.w, wreg[4 * k4 + 3], acc);
        }
        om[(size_t)r * D + lane] = __float2half(acc);
    }
}

// ---------- per-layer aggregate: fp16 gathers (128B/edge), 8-deep pipeline ----
__global__ __launch_bounds__(256) void aggregate_k(const __half* __restrict__ hw,
                                                   float* __restrict__ out,
                                                   const int* __restrict__ off,
                                                   const int2* __restrict__ csr_es,
                                                   const float* __restrict__ dinv,
                                                   const float* __restrict__ ball,
                                                   int layer, int relu) {
    int m = blockIdx.y;
    int n = blockIdx.x * 4 + (threadIdx.x >> 6);
    int lane = threadIdx.x & 63;
    const __half* hm = hw + (size_t)m * N_NODES * D;
    const int*    ob = off + m * OFF_STRIDE;
    const int2*   eb = csr_es + (size_t)m * N_EDGES;

    float dv  = dinv[m * N_NODES + n];
    float acc = dv * dv * __half2float(hm[(size_t)n * D + lane]);

    int e0 = ob[n], e1 = ob[n + 1];
    int e = e0;
    for (; e + 8 <= e1; e += 8) {
        int2 p0 = eb[e];     int2 p1 = eb[e + 1];
        int2 p2 = eb[e + 2]; int2 p3 = eb[e + 3];
        int2 p4 = eb[e + 4]; int2 p5 = eb[e + 5];
        int2 p6 = eb[e + 6]; int2 p7 = eb[e + 7];
        float g0 = __half2float(hm[(size_t)p0.x * D + lane]);
        float g1 = __half2float(hm[(size_t)p1.x * D + lane]);
        float g2 = __half2float(hm[(size_t)p2.x * D + lane]);
        float g3 = __half2float(hm[(size_t)p3.x * D + lane]);
        float g4 = __half2float(hm[(size_t)p4.x * D + lane]);
        float g5 = __half2float(hm[(size_t)p5.x * D + lane]);
        float g6 = __half2float(hm[(size_t)p6.x * D + lane]);
        float g7 = __half2float(hm[(size_t)p7.x * D + lane]);
        acc = fmaf(__int_as_float(p0.y), g0, acc);
        acc = fmaf(__int_as_float(p1.y), g1, acc);
        acc = fmaf(__int_as_float(p2.y), g2, acc);
        acc = fmaf(__int_as_float(p3.y), g3, acc);
        acc = fmaf(__int_as_float(p4.y), g4, acc);
        acc = fmaf(__int_as_float(p5.y), g5, acc);
        acc = fmaf(__int_as_float(p6.y), g6, acc);
        acc = fmaf(__int_as_float(p7.y), g7, acc);
    }
    for (; e < e1; e++) {
        int2 p = eb[e];
        acc = fmaf(__int_as_float(p.y), __half2float(hm[(size_t)p.x * D + lane]), acc);
    }

    acc += ball[(size_t)(m * N_LAYERS + layer) * D + lane];
    if (relu) acc = fmaxf(acc, 0.0f);
    out[(size_t)m * N_NODES * D + (size_t)n * D + lane] = acc;
}

// ---------- host ----------

extern "C" void kernel_launch(void* const* d_in, const int* in_sizes, int n_in,
                              void* d_out, int out_size, void* d_ws, size_t ws_size,
                              hipStream_t stream) {
    (void)in_sizes; (void)n_in; (void)out_size; (void)ws_size;
    const float* x  = (const float*)d_in[0];
    const int*   ei = (const int*)d_in[1];
    const float* W  = (const float*)d_in[2];
    const float* b  = (const float*)d_in[3];
    float* out = (float*)d_out;

    char* ws = (char*)d_ws;
    size_t o = 0;
    auto take = [&](size_t bytes) -> void* {
        void* p = ws + o;
        o = (o + bytes + 255) & ~(size_t)255;
        return p;
    };
    int*    deg      = (int*)   take((size_t)N_MEMBERS * N_NODES * 4);
    int*    cursor   = (int*)   take((size_t)N_MEMBERS * N_NODES * 4);
    float*  dinv     = (float*) take((size_t)N_MEMBERS * N_NODES * 4);
    int*    off      = (int*)   take((size_t)N_MEMBERS * OFF_STRIDE * 4);
    int*    bs       = (int*)   take((size_t)N_MEMBERS * 256 * 4);
    int2*   csr_es   = (int2*)  take((size_t)N_MEMBERS * N_EDGES * 8);
    __half* tbuf     = (__half*)take((size_t)N_MEMBERS * N_NODES * D * 2);
    float*  hbuf     = (float*) take((size_t)N_MEMBERS * N_NODES * D * 4);

    // zero deg + cursor (adjacent, both 256-padded)
    hipMemsetAsync(deg, 0, 2 * (size_t)N_MEMBERS * N_NODES * 4, stream);

    count_deg_k<<<dim3(N_EDGES / 256, N_MEMBERS), 256, 0, stream>>>(ei, deg);
    dinv_k<<<dim3((N_MEMBERS * N_NODES) / 256), 256, 0, stream>>>(deg, dinv);
    blocksum_k<<<dim3(N_NODES / 256, N_MEMBERS), 256, 0, stream>>>(deg, bs);
    scan_bs_k<<<dim3(N_MEMBERS), 256, 0, stream>>>(bs);
    scan_off_k<<<dim3(N_NODES / 256, N_MEMBERS), 256, 0, stream>>>(deg, bs, off);
    fill_k<<<dim3(N_EDGES / 256, N_MEMBERS), 256, 0, stream>>>(ei, off, cursor, dinv, csr_es);

    const float* hin = x;
    for (int j = 0; j < N_LAYERS; j++) {
        gemm_k<<<dim3(N_NODES / 128, N_MEMBERS), 256, 0, stream>>>(hin, W, tbuf, j);
        float* dst = (j == N_LAYERS - 1) ? out : hbuf;
        aggregate_k<<<dim3(N_NODES / 4, N_MEMBERS), 256, 0, stream>>>(
            tbuf, dst, off, csr_es, dinv, b, j, (j < N_LAYERS - 1) ? 1 : 0);
        hin = hbuf;
    }
}

// Round 4
// 1491.107 us; speedup vs baseline: 1.4871x; 1.1574x over previous
//
#include <hip/hip_runtime.h>
#include <hip/hip_fp16.h>
#include <math.h>

#define N_MEMBERS 2
#define N_NODES   65536
#define N_EDGES   1048576
#define N_LAYERS  12
#define D         64
#define OFF_STRIDE (N_NODES + 1)
#define NODE_MASK (N_NODES - 1)

// ---------- preprocessing ----------

__global__ __launch_bounds__(256) void count_deg_k(const int* __restrict__ ei,
                                                   int* __restrict__ deg) {
    int e = blockIdx.x * 256 + threadIdx.x;
    int m = blockIdx.y;
    int dst = ei[(size_t)(m * 2 + 1) * N_EDGES + e] & NODE_MASK;
    atomicAdd(&deg[m * N_NODES + dst], 1);
}

__global__ __launch_bounds__(256) void dinv_k(const int* __restrict__ deg,
                                              float* __restrict__ dinv) {
    int i = blockIdx.x * 256 + threadIdx.x;   // over 2*N_NODES
    dinv[i] = 1.0f / sqrtf((float)deg[i] + 1.0f);
}

// ---- parallel 2-level exclusive scan of deg -> off ----
__global__ __launch_bounds__(256) void blocksum_k(const int* __restrict__ deg,
                                                  int* __restrict__ bs) {
    int m = blockIdx.y, blk = blockIdx.x, t = threadIdx.x;
    __shared__ int sh[256];
    sh[t] = deg[m * N_NODES + blk * 256 + t];
    __syncthreads();
    for (int ofs = 128; ofs > 0; ofs >>= 1) {
        if (t < ofs) sh[t] += sh[t + ofs];
        __syncthreads();
    }
    if (t == 0) bs[m * 256 + blk] = sh[0];
}

__global__ __launch_bounds__(256) void scan_bs_k(int* __restrict__ bs) {
    int m = blockIdx.x, t = threadIdx.x;
    __shared__ int sh[256];
    sh[t] = bs[m * 256 + t];
    __syncthreads();
    for (int ofs = 1; ofs < 256; ofs <<= 1) {
        int v = sh[t];
        int a = (t >= ofs) ? sh[t - ofs] : 0;
        __syncthreads();
        sh[t] = v + a;
        __syncthreads();
    }
    bs[m * 256 + t] = (t == 0) ? 0 : sh[t - 1];   // exclusive
}

__global__ __launch_bounds__(256) void scan_off_k(const int* __restrict__ deg,
                                                  const int* __restrict__ bs,
                                                  int* __restrict__ off) {
    int m = blockIdx.y, blk = blockIdx.x, t = threadIdx.x;
    int i = blk * 256 + t;
    int d = deg[m * N_NODES + i];
    __shared__ int sh[256];
    sh[t] = d;
    __syncthreads();
    for (int ofs = 1; ofs < 256; ofs <<= 1) {
        int v = sh[t];
        int a = (t >= ofs) ? sh[t - ofs] : 0;
        __syncthreads();
        sh[t] = v + a;
        __syncthreads();
    }
    off[m * OFF_STRIDE + i] = bs[m * 256 + blk] + sh[t] - d;  // exclusive
    if (i == N_NODES - 1) off[m * OFF_STRIDE + N_NODES] = N_EDGES;
}

// ---- CSR fill: one combined 8B (src, norm) store per edge ----
__global__ __launch_bounds__(256) void fill_k(const int* __restrict__ ei,
                                              const int* __restrict__ off,
                                              int* __restrict__ cursor,
                                              const float* __restrict__ dinv,
                                              int2* __restrict__ csr_es) {
    int e = blockIdx.x * 256 + threadIdx.x;
    int m = blockIdx.y;
    int src = ei[(size_t)(m * 2 + 0) * N_EDGES + e] & NODE_MASK;
    int dst = ei[(size_t)(m * 2 + 1) * N_EDGES + e] & NODE_MASK;
    int pos = off[m * OFF_STRIDE + dst] + atomicAdd(&cursor[m * N_NODES + dst], 1);
    float nrm = dinv[m * N_NODES + src] * dinv[m * N_NODES + dst];
    csr_es[(size_t)m * N_EDGES + pos] = make_int2(src, __float_as_int(nrm));
}

// ---------- per-layer: hw = h @ W[m][layer] (fp16 out, LDS-staged h) ----------
__global__ __launch_bounds__(256) void gemm_k(const float* __restrict__ h,
                                              const float* __restrict__ Wall,
                                              __half* __restrict__ hw, int layer) {
    int m = blockIdx.y;
    const float* Wg = Wall + (size_t)(m * N_LAYERS + layer) * D * D;
    __shared__ float Wsh[D * D];        // 16 KB
    __shared__ float Hsh[128 * D];      // 32 KB
    for (int i = threadIdx.x; i < D * D / 4; i += 256)
        ((float4*)Wsh)[i] = ((const float4*)Wg)[i];
    int n0 = blockIdx.x * 128;
    const float* hm = h + (size_t)m * N_NODES * D + (size_t)n0 * D;
    for (int i = threadIdx.x; i < 128 * D / 4; i += 256)
        ((float4*)Hsh)[i] = ((const float4*)hm)[i];
    __syncthreads();

    int lane = threadIdx.x & 63;
    int wav  = threadIdx.x >> 6;
    float wreg[D];
    #pragma unroll
    for (int k = 0; k < D; k++) wreg[k] = Wsh[k * D + lane];

    __half* om = hw + (size_t)m * N_NODES * D + (size_t)n0 * D;
    for (int r = wav * 32; r < wav * 32 + 32; r++) {
        const float4* row = (const float4*)(Hsh + r * D);
        float acc = 0.0f;
        #pragma unroll
        for (int k4 = 0; k4 < D / 4; k4++) {
            float4 a = row[k4];
            acc = fmaf(a.x, wreg[4 * k4 + 0], acc);
            acc = fmaf(a.y, wreg[4 * k4 + 1], acc);
            acc = fmaf(a.z, wreg[4 * k4 + 2], acc);
            acc = fmaf(a.w, wreg[4 * k4 + 3], acc);
        }
        om[(size_t)r * D + lane] = __float2half(acc);
    }
}

// ---------- per-layer aggregate: 4 edges per wave gather instruction ----------
// lane = (sub = lane>>4, fg = lane&15). Each lane gathers ushort4 (4 fp16
// features of feature-group fg) of edge e+sub; accumulates float4. End:
// butterfly reduce over sub (xor 16, 32), lanes 0-15 store float4 (256B/row).
__device__ __forceinline__ float4 cvt4(ushort4 u) {
    union { ushort2 us[2]; __half2 h2[2]; } c;
    c.us[0] = make_ushort2(u.x, u.y);
    c.us[1] = make_ushort2(u.z, u.w);
    float2 a = __half22float2(c.h2[0]);
    float2 b = __half22float2(c.h2[1]);
    return make_float4(a.x, a.y, b.x, b.y);
}

__global__ __launch_bounds__(256) void aggregate_k(const __half* __restrict__ hw,
                                                   float* __restrict__ out,
                                                   const int* __restrict__ off,
                                                   const int2* __restrict__ csr_es,
                                                   const float* __restrict__ dinv,
                                                   const float* __restrict__ ball,
                                                   int layer, int relu) {
    int m = blockIdx.y;
    int n = blockIdx.x * 4 + (threadIdx.x >> 6);
    int lane = threadIdx.x & 63;
    int fg   = lane & 15;
    int sub  = lane >> 4;
    const ushort4* hm4 = (const ushort4*)(hw + (size_t)m * N_NODES * D);
    const int*     ob  = off + m * OFF_STRIDE;
    const int2*    eb  = csr_es + (size_t)m * N_EDGES;

    float4 acc = make_float4(0.f, 0.f, 0.f, 0.f);
    int e0 = ob[n], e1 = ob[n + 1];
    #pragma unroll 2
    for (int e = e0; e < e1; e += 4) {
        int ee  = e + sub;
        int idx = (ee < e1) ? ee : (e1 - 1);
        int2 p  = eb[idx];
        float w = (ee < e1) ? __int_as_float(p.y) : 0.0f;
        float4 g = cvt4(hm4[(size_t)p.x * 16 + fg]);
        acc.x = fmaf(w, g.x, acc.x);
        acc.y = fmaf(w, g.y, acc.y);
        acc.z = fmaf(w, g.z, acc.z);
        acc.w = fmaf(w, g.w, acc.w);
    }
    // reduce over sub (lanes with equal fg): xor 16, 32
    #pragma unroll
    for (int msk = 16; msk < 64; msk <<= 1) {
        acc.x += __shfl_xor(acc.x, msk);
        acc.y += __shfl_xor(acc.y, msk);
        acc.z += __shfl_xor(acc.z, msk);
        acc.w += __shfl_xor(acc.w, msk);
    }

    // self-loop + bias + relu (all lanes compute; lanes 0-15 store)
    float dv  = dinv[m * N_NODES + n];
    float dv2 = dv * dv;
    float4 s  = cvt4(hm4[(size_t)n * 16 + fg]);
    float4 bi = ((const float4*)(ball + (size_t)(m * N_LAYERS + layer) * D))[fg];
    acc.x = fmaf(dv2, s.x, acc.x) + bi.x;
    acc.y = fmaf(dv2, s.y, acc.y) + bi.y;
    acc.z = fmaf(dv2, s.z, acc.z) + bi.z;
    acc.w = fmaf(dv2, s.w, acc.w) + bi.w;
    if (relu) {
        acc.x = fmaxf(acc.x, 0.f);
        acc.y = fmaxf(acc.y, 0.f);
        acc.z = fmaxf(acc.z, 0.f);
        acc.w = fmaxf(acc.w, 0.f);
    }
    if (lane < 16)
        ((float4*)(out + (size_t)m * N_NODES * D + (size_t)n * D))[lane] = acc;
}

// ---------- host ----------

extern "C" void kernel_launch(void* const* d_in, const int* in_sizes, int n_in,
                              void* d_out, int out_size, void* d_ws, size_t ws_size,
                              hipStream_t stream) {
    (void)in_sizes; (void)n_in; (void)out_size; (void)ws_size;
    const float* x  = (const float*)d_in[0];
    const int*   ei = (const int*)d_in[1];
    const float* W  = (const float*)d_in[2];
    const float* b  = (const float*)d_in[3];
    float* out = (float*)d_out;

    char* ws = (char*)d_ws;
    size_t o = 0;
    auto take = [&](size_t bytes) -> void* {
        void* p = ws + o;
        o = (o + bytes + 255) & ~(size_t)255;
        return p;
    };
    int*    deg      = (int*)   take((size_t)N_MEMBERS * N_NODES * 4);
    int*    cursor   = (int*)   take((size_t)N_MEMBERS * N_NODES * 4);
    float*  dinv     = (float*) take((size_t)N_MEMBERS * N_NODES * 4);
    int*    off      = (int*)   take((size_t)N_MEMBERS * OFF_STRIDE * 4);
    int*    bs       = (int*)   take((size_t)N_MEMBERS * 256 * 4);
    int2*   csr_es   = (int2*)  take((size_t)N_MEMBERS * N_EDGES * 8);
    __half* tbuf     = (__half*)take((size_t)N_MEMBERS * N_NODES * D * 2);
    float*  hbuf     = (float*) take((size_t)N_MEMBERS * N_NODES * D * 4);

    // zero deg + cursor (adjacent, both 256-padded)
    hipMemsetAsync(deg, 0, 2 * (size_t)N_MEMBERS * N_NODES * 4, stream);

    count_deg_k<<<dim3(N_EDGES / 256, N_MEMBERS), 256, 0, stream>>>(ei, deg);
    dinv_k<<<dim3((N_MEMBERS * N_NODES) / 256), 256, 0, stream>>>(deg, dinv);
    blocksum_k<<<dim3(N_NODES / 256, N_MEMBERS), 256, 0, stream>>>(deg, bs);
    scan_bs_k<<<dim3(N_MEMBERS), 256, 0, stream>>>(bs);
    scan_off_k<<<dim3(N_NODES / 256, N_MEMBERS), 256, 0, stream>>>(deg, bs, off);
    fill_k<<<dim3(N_EDGES / 256, N_MEMBERS), 256, 0, stream>>>(ei, off, cursor, dinv, csr_es);

    const float* hin = x;
    for (int j = 0; j < N_LAYERS; j++) {
        gemm_k<<<dim3(N_NODES / 128, N_MEMBERS), 256, 0, stream>>>(hin, W, tbuf, j);
        float* dst = (j == N_LAYERS - 1) ? out : hbuf;
        aggregate_k<<<dim3(N_NODES / 4, N_MEMBERS), 256, 0, stream>>>(
            tbuf, dst, off, csr_es, dinv, b, j, (j < N_LAYERS - 1) ? 1 : 0);
        hin = hbuf;
    }
}